// Round 8
// baseline (204.795 us; speedup 1.0000x reference)
//
#include <hip/hip_runtime.h>
#include <cstdint>
#include <cstddef>

typedef unsigned short u16;
typedef unsigned int u32;
typedef __attribute__((ext_vector_type(8))) __bf16 bf16x8;
typedef __attribute__((ext_vector_type(8))) u16 u16x8;
typedef __attribute__((ext_vector_type(4))) float f32x4;

#define N_SEQ   2048
#define HDIM    32
// (hd^-0.5) * log2(e): Q pre-scaled so attn uses bare exp2
#define QSCALE_LOG2E 0.2550540261150831f

#if __has_builtin(__builtin_amdgcn_exp2f)
#define EXP2(x) __builtin_amdgcn_exp2f(x)
#else
#define EXP2(x) exp2f(x)
#endif

__device__ __forceinline__ u16 f2bf(float f){
  union { float f; u32 i; } v; v.f = f;
  return (u16)((v.i + 0x7FFFu + ((v.i >> 16) & 1u)) >> 16);
}
__device__ __forceinline__ u32 fbits(float f){
  union { float f; u32 i; } v; v.f = f; return v.i;
}
__device__ __forceinline__ u32 pk2bf(float a, float b){
  return ((fbits(a) + 0x8000u) >> 16) | ((fbits(b) + 0x8000u) & 0xFFFF0000u);
}
__device__ __forceinline__ f32x4 mfma_bf16(bf16x8 a, bf16x8 b, f32x4 c){
  return __builtin_amdgcn_mfma_f32_16x16x32_bf16(a, b, c, 0, 0, 0);
}
union U8 { u16x8 u; bf16x8 b; };
union U2 { u32 w[2]; uint64_t q; };

// ---------------------------------------------------------------------------
// Kernel 1: W [256][768] fp32 -> Wt [768][256] bf16 (transposed)
// ---------------------------------------------------------------------------
__global__ __launch_bounds__(256) void wt_kernel(const float* __restrict__ W,
                                                 u16* __restrict__ Wt){
  __shared__ u16 T[32][33];
  int t  = threadIdx.x;
  int tx = t & 31, ty = t >> 5;
  int n0 = blockIdx.x * 32;
  int k0 = blockIdx.y * 32;
#pragma unroll
  for (int i = 0; i < 4; ++i){
    int kk = ty + i*8;
    T[kk][tx] = f2bf(W[(k0+kk)*768 + n0 + tx]);
  }
  __syncthreads();
#pragma unroll
  for (int i = 0; i < 4; ++i){
    int nn = ty + i*8;
    Wt[(n0+nn)*256 + k0 + tx] = T[tx][nn];
  }
}

// ---------------------------------------------------------------------------
// Kernel 2: QKV = x @ W + b.  1D grid 1536, XCD-swizzled: all 12 n-blocks of
// one m-tile land on one XCD (xcd = m_tile & 7) -> x tile read from HBM once
// per XCD, L2-shared.  Register A-frags; V epilogue via LDS for contiguous
// 128B token-major stores.
// ---------------------------------------------------------------------------
__global__ __launch_bounds__(256) void qkv_kernel(const float* __restrict__ X,
                                                  const u16* __restrict__ Wt,
                                                  const float* __restrict__ bias,
                                                  u16* __restrict__ Q,
                                                  u16* __restrict__ K,
                                                  u16* __restrict__ Vt){
  __shared__ u16 Vs[64][66];              // [c_local][token], +2 pad
  int bid = blockIdx.x;
  int xcd = bid & 7;
  int idx = bid >> 3;                     // 0..191
  int mt  = 8*(idx & 15) + xcd;           // m-tile 0..127, xcd = mt & 7
  int nb  = idx >> 4;                     // 0..11
  int tid = threadIdx.x;
  int wave = tid >> 6, lane = tid & 63;
  int l16 = lane & 15, quad = lane >> 4;
  int m0 = mt * 64;
  int mw = m0 + wave * 16;                // this wave's 16 token rows
  int n0 = nb * 64;                       // 64 output cols (uniform q/k/v)
  const int three = n0 >> 8;              // 0=q 1=k 2=v (block-uniform)

  // ---- A-frags: x row (mw+l16), 8 chunks of 8 floats -> bf16 ----
  const float* xr = X + (mw + l16) * 256 + quad * 8;
  U8 af[8];
#pragma unroll
  for (int k = 0; k < 8; ++k){
    f32x4 lo = *(const f32x4*)(xr + k*32);
    f32x4 hi = *(const f32x4*)(xr + k*32 + 4);
    union { u32 w[4]; u16x8 u; } pk;
    pk.w[0] = pk2bf(lo[0], lo[1]);
    pk.w[1] = pk2bf(lo[2], lo[3]);
    pk.w[2] = pk2bf(hi[0], hi[1]);
    pk.w[3] = pk2bf(hi[2], hi[3]);
    af[k].u = pk.u;
  }

  // ---- MFMA over K=256 ----
  f32x4 acc[4] = {};
#pragma unroll
  for (int k = 0; k < 8; ++k)
#pragma unroll
    for (int s = 0; s < 4; ++s){
      U8 b; b.u = *(const u16x8*)(Wt + (n0 + s*16 + l16)*256 + k*32 + quad*8);
      acc[s] = mfma_bf16(af[k].b, b.b, acc[s]);
    }

  // ---- epilogue ----
  int b_ = m0 >> 11, nseq0 = m0 & 2047;   // block rows all in one batch
#pragma unroll
  for (int s = 0; s < 4; ++s){
    int cl = s*16 + l16;                  // col within block [0,64)
    int c = n0 + cl;
    float bv = bias[c];
    int h = (c >> 5) & 7;
    int d = c & 31;
    int tok = wave*16 + quad*4;           // first of 4 consecutive tokens
    if (three == 2){
      U2 pk;
      pk.w[0] = pk2bf(acc[s][0] + bv, acc[s][1] + bv);
      pk.w[1] = pk2bf(acc[s][2] + bv, acc[s][3] + bv);
      *(uint64_t*)(&Vs[cl][tok]) = pk.q;
    } else {
      float scl = (three == 0) ? QSCALE_LOG2E : 1.0f;
      u16* dst = (three == 0) ? Q : K;
      int bh = b_*8 + h;
#pragma unroll
      for (int r = 0; r < 4; ++r)
        dst[(bh*N_SEQ + nseq0 + tok + r)*HDIM + d] = f2bf((acc[s][r] + bv) * scl);
    }
  }

  if (three == 2){
    __syncthreads();
#pragma unroll
    for (int i = 0; i < 16; ++i){
      int cl = wave*16 + i;
      int c = n0 + cl;
      int h = (c >> 5) & 7, d = c & 31;
      int bh = b_*8 + h;
      Vt[(bh*HDIM + d)*N_SEQ + nseq0 + lane] = Vs[cl][lane];
    }
  }
}

// ---------------------------------------------------------------------------
// Kernel 3: attention.  1D grid 2048, XCD-swizzled: bh = (bid&7)*4 +
// ((bid>>3)&3) -> each XCD serves only 4 bh (1 MB K/V) => L2-resident.
// Block = 2 balanced items (pairs {2p,2p+1} cost 32 / {64+q,127-q} cost 49);
// per item 4 waves k-split (stride 4).  Single P buffer (18 KB LDS) ->
// 6 blocks/CU.  K prefetched 1 tile ahead; p = exp2(S) (Q pre-scaled).
// ---------------------------------------------------------------------------
__global__ __launch_bounds__(256, 6) void attn_kernel(const u16* __restrict__ Q,
                                                      const u16* __restrict__ Kg,
                                                      const u16* __restrict__ Vt,
                                                      float* __restrict__ out){
  __shared__ __align__(16) u16  Ps[4][16][72];    // per-wave P, stride 144 B
  __shared__ __align__(8) float Obuf[4][16][34];
  __shared__ float Lbuf[4][16];
  int bid = blockIdx.x;
  int bh = (bid & 7)*4 + ((bid >> 3) & 3);
  int p  = bid >> 5;                      // 0..63
  int tid = threadIdx.x, wave = tid >> 6, lane = tid & 63;
  int l16 = lane & 15, quad = lane >> 4;

  int glist[2];
  if (p < 32){ glist[0] = 2*p;      glist[1] = 2*p + 1; }
  else       { int q = p - 32; glist[0] = 64 + q; glist[1] = 127 - q; }

  const u16* Qb = Q  + bh * (N_SEQ*HDIM);
  const u16* Kb = Kg + bh * (N_SEQ*HDIM);
  const u16* Vb = Vt + bh * (N_SEQ*HDIM);

  U8 onesu;
#pragma unroll
  for (int q = 0; q < 8; ++q) onesu.u[q] = 0x3F80;  // bf16 1.0
  bf16x8 ones = onesu.b;

  u16 (*P)[72] = Ps[wave];

  for (int it = 0; it < 2; ++it){
    int g  = glist[it];
    int r0 = g * 16;
    const int  T       = (r0 < 1024) ? 16 : (r0 >> 6) + 1;
    const bool hasMask = (r0 >= 1024);
    const int  iq      = r0 + l16;

    U8 qt; qt.u = *(const u16x8*)(Qb + (r0 + l16)*HDIM + quad*8);
    bf16x8 qfrag = qt.b;

    f32x4 O0 = {}, O1 = {}, L = {};

    // preload K for first tile
    U8 kfA[4], kfB[4];
#pragma unroll
    for (int s = 0; s < 4; ++s)
      kfA[s].u = *(const u16x8*)(Kb + (wave*64 + s*16 + l16)*HDIM + quad*8);

    for (int t = wave; t < T; t += 4){
      int k0 = t * 64;
      // prefetch K(t+4) (clamped, wave-uniform)
      int kn = (t + 4 < T) ? (k0 + 256) : k0;
#pragma unroll
      for (int s = 0; s < 4; ++s)
        kfB[s].u = *(const u16x8*)(Kb + (kn + s*16 + l16)*HDIM + quad*8);
      // V for this tile (consumed after exp section; L2-resident)
      U8 vf[2][2];
#pragma unroll
      for (int kc = 0; kc < 2; ++kc)
#pragma unroll
        for (int nd = 0; nd < 2; ++nd)
          vf[kc][nd].u = *(const u16x8*)(Vb + (nd*16 + l16)*N_SEQ + k0 + kc*32 + quad*8);

      // S^T = K Q^T : ST[s][r] = score(key k0+s*16+quad*4+r, query r0+l16)
      f32x4 ST[4];
#pragma unroll
      for (int s = 0; s < 4; ++s){
        f32x4 z = {};
        ST[s] = mfma_bf16(kfA[s].b, qfrag, z);
      }

      // p = exp2(s); pack 4 consecutive keys -> one b64 LDS store
      if (hasMask && (t == T - 1)){
#pragma unroll
        for (int s = 0; s < 4; ++s){
          int jb = k0 + s*16 + quad*4;
          float p0 = (jb+0 > iq) ? 0.0f : EXP2(ST[s][0]);
          float p1 = (jb+1 > iq) ? 0.0f : EXP2(ST[s][1]);
          float p2 = (jb+2 > iq) ? 0.0f : EXP2(ST[s][2]);
          float p3 = (jb+3 > iq) ? 0.0f : EXP2(ST[s][3]);
          U2 pk; pk.w[0] = pk2bf(p0, p1); pk.w[1] = pk2bf(p2, p3);
          *(uint64_t*)(&P[l16][s*16 + quad*4]) = pk.q;
        }
      } else {
#pragma unroll
        for (int s = 0; s < 4; ++s){
          U2 pk;
          pk.w[0] = pk2bf(EXP2(ST[s][0]), EXP2(ST[s][1]));
          pk.w[1] = pk2bf(EXP2(ST[s][2]), EXP2(ST[s][3]));
          *(uint64_t*)(&P[l16][s*16 + quad*4]) = pk.q;
        }
      }

      // PV + denominator (ones-MFMA); LDS store->load order compiler-enforced
#pragma unroll
      for (int kc = 0; kc < 2; ++kc){
        U8 pf; pf.u = *(const u16x8*)(&P[l16][kc*32 + quad*8]);
        O0 = mfma_bf16(pf.b, vf[kc][0].b, O0);
        O1 = mfma_bf16(pf.b, vf[kc][1].b, O1);
        L  = mfma_bf16(pf.b, ones, L);
      }

#pragma unroll
      for (int s = 0; s < 4; ++s) kfA[s] = kfB[s];
    }

    // ---- combine the 4 key-splits, store ----
#pragma unroll
    for (int r = 0; r < 4; ++r){
      Obuf[wave][quad*4 + r][l16]      = O0[r];
      Obuf[wave][quad*4 + r][16 + l16] = O1[r];
    }
    if (l16 == 0){
#pragma unroll
      for (int r = 0; r < 4; ++r) Lbuf[wave][quad*4 + r] = L[r];
    }
    __syncthreads();

    {
      int row = tid >> 4;              // 0..15
      int c2  = (tid & 15) * 2;        // even col in [0,32)
      float a = 0.f, b2 = 0.f, Ls = 0.f;
#pragma unroll
      for (int w = 0; w < 4; ++w){
        a  += Obuf[w][row][c2];
        b2 += Obuf[w][row][c2 + 1];
        Ls += Lbuf[w][row];
      }
      float inv = 1.0f / Ls;
      int b_ = bh >> 3, h = bh & 7;
      float2 st; st.x = a * inv; st.y = b2 * inv;
      *(float2*)(&out[(b_*N_SEQ + r0 + row)*256 + h*32 + c2]) = st;
    }
    __syncthreads();   // Obuf/Lbuf reuse by next item
  }
}

// ---------------------------------------------------------------------------
extern "C" void kernel_launch(void* const* d_in, const int* in_sizes, int n_in,
                              void* d_out, int out_size, void* d_ws, size_t ws_size,
                              hipStream_t stream) {
  const float* x    = (const float*)d_in[0];   // [4,2048,256] fp32
  const float* W    = (const float*)d_in[1];   // [256,768]    fp32
  const float* bias = (const float*)d_in[2];   // [768]        fp32
  float* out = (float*)d_out;                  // [4,2048,256] fp32

  char* ws = (char*)d_ws;
  u16* Wt    = (u16*)(ws);                     // 393,216 B
  u16* Kbuf  = (u16*)(ws + 393216);            // 4 MB
  u16* Vtbuf = (u16*)(ws + 393216 + 4194304);  // 4 MB
  u16* Qbuf  = (u16*)(ws + 393216 + 2*4194304);// 4 MB

  wt_kernel  <<<dim3(24, 8), 256, 0, stream>>>(W, Wt);
  qkv_kernel <<<dim3(1536),  256, 0, stream>>>(x, Wt, bias, Qbuf, Kbuf, Vtbuf);
  attn_kernel<<<dim3(2048),  256, 0, stream>>>(Qbuf, Kbuf, Vtbuf, out);
}

// Round 9
// 160.045 us; speedup vs baseline: 1.2796x; 1.2796x over previous
//
#include <hip/hip_runtime.h>
#include <cstdint>
#include <cstddef>

typedef unsigned short u16;
typedef unsigned int u32;
typedef __attribute__((ext_vector_type(8))) __bf16 bf16x8;
typedef __attribute__((ext_vector_type(8))) u16 u16x8;
typedef __attribute__((ext_vector_type(4))) float f32x4;

#define N_SEQ   2048
#define HDIM    32
// (hd^-0.5) * log2(e): Q pre-scaled so attn uses bare exp2
#define QSCALE_LOG2E 0.2550540261150831f

#if __has_builtin(__builtin_amdgcn_exp2f)
#define EXP2(x) __builtin_amdgcn_exp2f(x)
#else
#define EXP2(x) exp2f(x)
#endif

__device__ __forceinline__ u16 f2bf(float f){
  union { float f; u32 i; } v; v.f = f;
  return (u16)((v.i + 0x7FFFu + ((v.i >> 16) & 1u)) >> 16);
}
__device__ __forceinline__ u32 fbits(float f){
  union { float f; u32 i; } v; v.f = f; return v.i;
}
__device__ __forceinline__ u32 pk2bf(float a, float b){
  return ((fbits(a) + 0x8000u) >> 16) | ((fbits(b) + 0x8000u) & 0xFFFF0000u);
}
__device__ __forceinline__ f32x4 mfma_bf16(bf16x8 a, bf16x8 b, f32x4 c){
  return __builtin_amdgcn_mfma_f32_16x16x32_bf16(a, b, c, 0, 0, 0);
}
union U8 { u16x8 u; bf16x8 b; };
union U2 { u32 w[2]; uint64_t q; };

// ---------------------------------------------------------------------------
// Kernel 1: W [256][768] fp32 -> Wt [768][256] bf16 (transposed)
// ---------------------------------------------------------------------------
__global__ __launch_bounds__(256) void wt_kernel(const float* __restrict__ W,
                                                 u16* __restrict__ Wt){
  __shared__ u16 T[32][33];
  int t  = threadIdx.x;
  int tx = t & 31, ty = t >> 5;
  int n0 = blockIdx.x * 32;
  int k0 = blockIdx.y * 32;
#pragma unroll
  for (int i = 0; i < 4; ++i){
    int kk = ty + i*8;
    T[kk][tx] = f2bf(W[(k0+kk)*768 + n0 + tx]);
  }
  __syncthreads();
#pragma unroll
  for (int i = 0; i < 4; ++i){
    int nn = ty + i*8;
    Wt[(n0+nn)*256 + k0 + tx] = T[tx][nn];
  }
}

// ---------------------------------------------------------------------------
// Kernel 2: QKV = x @ W + b.  1D grid 1536, XCD-swizzled (all 12 n-blocks of
// an m-tile on one XCD).  Register A-frags from global x.  ALL outputs now go
// through LDS staging so global stores are coalesced 16B chunks:
//   Q/K: Ts[tok][col] (stride 68, conflict-free) -> [bh][tok][d] 4KB head-tiles
//   V:   Vs[col][tok] (stride 68) -> Vt[bh][d][tok] 128B token runs
// ---------------------------------------------------------------------------
__global__ __launch_bounds__(256) void qkv_kernel(const float* __restrict__ X,
                                                  const u16* __restrict__ Wt,
                                                  const float* __restrict__ bias,
                                                  u16* __restrict__ Q,
                                                  u16* __restrict__ K,
                                                  u16* __restrict__ Vt){
  __shared__ __align__(16) u16 S[64*68];  // 8704 B staging
  int bid = blockIdx.x;
  int xcd = bid & 7;
  int idx = bid >> 3;                     // 0..191
  int mt  = 8*(idx & 15) + xcd;           // m-tile 0..127
  int nb  = idx >> 4;                     // 0..11
  int tid = threadIdx.x;
  int wave = tid >> 6, lane = tid & 63;
  int l16 = lane & 15, quad = lane >> 4;
  int m0 = mt * 64;
  int mw = m0 + wave * 16;
  int n0 = nb * 64;                       // 64 output cols (uniform q/k/v)
  const int three = n0 >> 8;              // 0=q 1=k 2=v (block-uniform)

  // ---- A-frags: x row (mw+l16), 8 chunks of 8 floats -> bf16 ----
  const float* xr = X + (mw + l16) * 256 + quad * 8;
  U8 af[8];
#pragma unroll
  for (int k = 0; k < 8; ++k){
    f32x4 lo = *(const f32x4*)(xr + k*32);
    f32x4 hi = *(const f32x4*)(xr + k*32 + 4);
    union { u32 w[4]; u16x8 u; } pk;
    pk.w[0] = pk2bf(lo[0], lo[1]);
    pk.w[1] = pk2bf(lo[2], lo[3]);
    pk.w[2] = pk2bf(hi[0], hi[1]);
    pk.w[3] = pk2bf(hi[2], hi[3]);
    af[k].u = pk.u;
  }

  // ---- MFMA over K=256 ----
  f32x4 acc[4] = {};
#pragma unroll
  for (int k = 0; k < 8; ++k)
#pragma unroll
    for (int s = 0; s < 4; ++s){
      U8 b; b.u = *(const u16x8*)(Wt + (n0 + s*16 + l16)*256 + k*32 + quad*8);
      acc[s] = mfma_bf16(af[k].b, b.b, acc[s]);
    }

  // ---- epilogue ----
  int b_ = m0 >> 11, nseq0 = m0 & 2047;   // block rows all in one batch
  if (three == 2){
    // V: stage [col][tok]
#pragma unroll
    for (int s = 0; s < 4; ++s){
      int cl = s*16 + l16;
      float bv = bias[n0 + cl];
      int tok = wave*16 + quad*4;
      U2 pk;
      pk.w[0] = pk2bf(acc[s][0] + bv, acc[s][1] + bv);
      pk.w[1] = pk2bf(acc[s][2] + bv, acc[s][3] + bv);
      *(uint64_t*)(&S[cl*68 + tok]) = pk.q;
    }
    __syncthreads();
#pragma unroll
    for (int i = 0; i < 16; ++i){
      int cl = wave*16 + i;
      int c = n0 + cl;
      int h = (c >> 5) & 7, d = c & 31;
      int bh = b_*8 + h;
      Vt[(bh*HDIM + d)*N_SEQ + nseq0 + lane] = S[cl*68 + lane];
    }
  } else {
    // Q/K: stage token-major [tok][col]
    float scl = (three == 0) ? QSCALE_LOG2E : 1.0f;
#pragma unroll
    for (int s = 0; s < 4; ++s){
      int cl = s*16 + l16;
      float bv = bias[n0 + cl];
#pragma unroll
      for (int r = 0; r < 4; ++r)
        S[(wave*16 + quad*4 + r)*68 + cl] = f2bf((acc[s][r] + bv) * scl);
    }
    __syncthreads();
    u16* dst = (three == 0) ? Q : K;
#pragma unroll
    for (int j = 0; j < 2; ++j){
      int unit = tid + j*256;             // 512 units: tok x ph x chunk
      int tok = unit & 63;
      int rest = unit >> 6;               // 0..7
      int ph = rest >> 2, chunk = rest & 3;
      int h = ((n0 >> 5) + ph) & 7;
      int bh = b_*8 + h;
      u16x8 v = *(const u16x8*)(&S[tok*68 + ph*32 + chunk*8]);
      *(u16x8*)(&dst[(bh*N_SEQ + nseq0 + tok)*HDIM + chunk*8]) = v;
    }
  }
}

// ---------------------------------------------------------------------------
// Kernel 3: attention.  1D grid 2048, XCD-swizzled: bh = (bid&7)*4 +
// ((bid>>3)&3) -> each XCD serves 4 bh (~1.5 MB working set) => L2-resident.
// Block = 2 balanced items (pairs {2p,2p+1} cost 32 / {64+q,127-q} cost 49);
// per item 4 waves k-split (stride 4).  Single P buffer, 18 KB LDS.
// launch_bounds(256,4): VGPR cap 128 -- kernel needs ~70, NO SPILL (R8 bug).
// ---------------------------------------------------------------------------
__global__ __launch_bounds__(256, 4) void attn_kernel(const u16* __restrict__ Q,
                                                      const u16* __restrict__ Kg,
                                                      const u16* __restrict__ Vt,
                                                      float* __restrict__ out){
  __shared__ __align__(16) u16  Ps[4][16][72];    // per-wave P, stride 144 B
  __shared__ __align__(8) float Obuf[4][16][34];
  __shared__ float Lbuf[4][16];
  int bid = blockIdx.x;
  int bh = (bid & 7)*4 + ((bid >> 3) & 3);
  int p  = bid >> 5;                      // 0..63
  int tid = threadIdx.x, wave = tid >> 6, lane = tid & 63;
  int l16 = lane & 15, quad = lane >> 4;

  int glist[2];
  if (p < 32){ glist[0] = 2*p;      glist[1] = 2*p + 1; }
  else       { int q = p - 32; glist[0] = 64 + q; glist[1] = 127 - q; }

  const u16* Qb = Q  + bh * (N_SEQ*HDIM);
  const u16* Kb = Kg + bh * (N_SEQ*HDIM);
  const u16* Vb = Vt + bh * (N_SEQ*HDIM);

  U8 onesu;
#pragma unroll
  for (int q = 0; q < 8; ++q) onesu.u[q] = 0x3F80;  // bf16 1.0
  bf16x8 ones = onesu.b;

  u16 (*P)[72] = Ps[wave];

  for (int it = 0; it < 2; ++it){
    int g  = glist[it];
    int r0 = g * 16;
    const int  T       = (r0 < 1024) ? 16 : (r0 >> 6) + 1;
    const bool hasMask = (r0 >= 1024);
    const int  iq      = r0 + l16;

    U8 qt; qt.u = *(const u16x8*)(Qb + (r0 + l16)*HDIM + quad*8);
    bf16x8 qfrag = qt.b;

    f32x4 O0 = {}, O1 = {}, L = {};

    // preload K for first tile
    U8 kfA[4], kfB[4];
#pragma unroll
    for (int s = 0; s < 4; ++s)
      kfA[s].u = *(const u16x8*)(Kb + (wave*64 + s*16 + l16)*HDIM + quad*8);

    for (int t = wave; t < T; t += 4){
      int k0 = t * 64;
      // prefetch K(t+4) (clamped, wave-uniform)
      int kn = (t + 4 < T) ? (k0 + 256) : k0;
#pragma unroll
      for (int s = 0; s < 4; ++s)
        kfB[s].u = *(const u16x8*)(Kb + (kn + s*16 + l16)*HDIM + quad*8);
      // V for this tile (L2-resident)
      U8 vf[2][2];
#pragma unroll
      for (int kc = 0; kc < 2; ++kc)
#pragma unroll
        for (int nd = 0; nd < 2; ++nd)
          vf[kc][nd].u = *(const u16x8*)(Vb + (nd*16 + l16)*N_SEQ + k0 + kc*32 + quad*8);

      // S^T = K Q^T : ST[s][r] = score(key k0+s*16+quad*4+r, query r0+l16)
      f32x4 ST[4];
#pragma unroll
      for (int s = 0; s < 4; ++s){
        f32x4 z = {};
        ST[s] = mfma_bf16(kfA[s].b, qfrag, z);
      }

      // p = exp2(s); pack 4 consecutive keys -> one b64 LDS store
      if (hasMask && (t == T - 1)){
#pragma unroll
        for (int s = 0; s < 4; ++s){
          int jb = k0 + s*16 + quad*4;
          float p0 = (jb+0 > iq) ? 0.0f : EXP2(ST[s][0]);
          float p1 = (jb+1 > iq) ? 0.0f : EXP2(ST[s][1]);
          float p2 = (jb+2 > iq) ? 0.0f : EXP2(ST[s][2]);
          float p3 = (jb+3 > iq) ? 0.0f : EXP2(ST[s][3]);
          U2 pk; pk.w[0] = pk2bf(p0, p1); pk.w[1] = pk2bf(p2, p3);
          *(uint64_t*)(&P[l16][s*16 + quad*4]) = pk.q;
        }
      } else {
#pragma unroll
        for (int s = 0; s < 4; ++s){
          U2 pk;
          pk.w[0] = pk2bf(EXP2(ST[s][0]), EXP2(ST[s][1]));
          pk.w[1] = pk2bf(EXP2(ST[s][2]), EXP2(ST[s][3]));
          *(uint64_t*)(&P[l16][s*16 + quad*4]) = pk.q;
        }
      }

      // PV + denominator (ones-MFMA); LDS store->load order compiler-enforced
#pragma unroll
      for (int kc = 0; kc < 2; ++kc){
        U8 pf; pf.u = *(const u16x8*)(&P[l16][kc*32 + quad*8]);
        O0 = mfma_bf16(pf.b, vf[kc][0].b, O0);
        O1 = mfma_bf16(pf.b, vf[kc][1].b, O1);
        L  = mfma_bf16(pf.b, ones, L);
      }

#pragma unroll
      for (int s = 0; s < 4; ++s) kfA[s] = kfB[s];
    }

    // ---- combine the 4 key-splits, store ----
#pragma unroll
    for (int r = 0; r < 4; ++r){
      Obuf[wave][quad*4 + r][l16]      = O0[r];
      Obuf[wave][quad*4 + r][16 + l16] = O1[r];
    }
    if (l16 == 0){
#pragma unroll
      for (int r = 0; r < 4; ++r) Lbuf[wave][quad*4 + r] = L[r];
    }
    __syncthreads();

    {
      int row = tid >> 4;              // 0..15
      int c2  = (tid & 15) * 2;        // even col in [0,32)
      float a = 0.f, b2 = 0.f, Ls = 0.f;
#pragma unroll
      for (int w = 0; w < 4; ++w){
        a  += Obuf[w][row][c2];
        b2 += Obuf[w][row][c2 + 1];
        Ls += Lbuf[w][row];
      }
      float inv = 1.0f / Ls;
      int b_ = bh >> 3, h = bh & 7;
      float2 st; st.x = a * inv; st.y = b2 * inv;
      *(float2*)(&out[(b_*N_SEQ + r0 + row)*256 + h*32 + c2]) = st;
    }
    __syncthreads();   // Obuf/Lbuf reuse by next item
  }
}

// ---------------------------------------------------------------------------
extern "C" void kernel_launch(void* const* d_in, const int* in_sizes, int n_in,
                              void* d_out, int out_size, void* d_ws, size_t ws_size,
                              hipStream_t stream) {
  const float* x    = (const float*)d_in[0];   // [4,2048,256] fp32
  const float* W    = (const float*)d_in[1];   // [256,768]    fp32
  const float* bias = (const float*)d_in[2];   // [768]        fp32
  float* out = (float*)d_out;                  // [4,2048,256] fp32

  char* ws = (char*)d_ws;
  u16* Wt    = (u16*)(ws);                     // 393,216 B
  u16* Kbuf  = (u16*)(ws + 393216);            // 4 MB
  u16* Vtbuf = (u16*)(ws + 393216 + 4194304);  // 4 MB
  u16* Qbuf  = (u16*)(ws + 393216 + 2*4194304);// 4 MB

  wt_kernel  <<<dim3(24, 8), 256, 0, stream>>>(W, Wt);
  qkv_kernel <<<dim3(1536),  256, 0, stream>>>(x, Wt, bias, Qbuf, Kbuf, Vtbuf);
  attn_kernel<<<dim3(2048),  256, 0, stream>>>(Qbuf, Kbuf, Vtbuf, out);
}

// Round 10
// 125.286 us; speedup vs baseline: 1.6346x; 1.2774x over previous
//
#include <hip/hip_runtime.h>
#include <cstdint>
#include <cstddef>

typedef unsigned short u16;
typedef unsigned int u32;
typedef __attribute__((ext_vector_type(8))) __bf16 bf16x8;
typedef __attribute__((ext_vector_type(8))) u16 u16x8;
typedef __attribute__((ext_vector_type(4))) float f32x4;

#define N_SEQ   2048
#define HDIM    32
// (hd^-0.5) * log2(e): Q pre-scaled so attn uses bare exp2
#define QSCALE_LOG2E 0.2550540261150831f

#if __has_builtin(__builtin_amdgcn_exp2f)
#define EXP2(x) __builtin_amdgcn_exp2f(x)
#else
#define EXP2(x) exp2f(x)
#endif

__device__ __forceinline__ u16 f2bf(float f){
  union { float f; u32 i; } v; v.f = f;
  return (u16)((v.i + 0x7FFFu + ((v.i >> 16) & 1u)) >> 16);
}
__device__ __forceinline__ u32 fbits(float f){
  union { float f; u32 i; } v; v.f = f; return v.i;
}
__device__ __forceinline__ u32 pk2bf(float a, float b){
  return ((fbits(a) + 0x8000u) >> 16) | ((fbits(b) + 0x8000u) & 0xFFFF0000u);
}
__device__ __forceinline__ f32x4 mfma_bf16(bf16x8 a, bf16x8 b, f32x4 c){
  return __builtin_amdgcn_mfma_f32_16x16x32_bf16(a, b, c, 0, 0, 0);
}
union U8 { u16x8 u; bf16x8 b; };
union U2 { u32 w[2]; uint64_t q; };

// ---------------------------------------------------------------------------
// Kernel 1: W [256][768] fp32 -> Wt [768][256] bf16 (transposed)
// ---------------------------------------------------------------------------
__global__ __launch_bounds__(256) void wt_kernel(const float* __restrict__ W,
                                                 u16* __restrict__ Wt){
  __shared__ u16 T[32][33];
  int t  = threadIdx.x;
  int tx = t & 31, ty = t >> 5;
  int n0 = blockIdx.x * 32;
  int k0 = blockIdx.y * 32;
#pragma unroll
  for (int i = 0; i < 4; ++i){
    int kk = ty + i*8;
    T[kk][tx] = f2bf(W[(k0+kk)*768 + n0 + tx]);
  }
  __syncthreads();
#pragma unroll
  for (int i = 0; i < 4; ++i){
    int nn = ty + i*8;
    Wt[(n0+nn)*256 + k0 + tx] = T[tx][nn];
  }
}

// ---------------------------------------------------------------------------
// Kernel 2: QKV = x @ W + b.  1D grid 1536, XCD-swizzled.  Register A-frags.
// LDS-staged coalesced stores.  V now stored TILED: Vt[bh][kb][d(32)][kk(32)]
// (kb = key>>5) so attn's V-fragment loads are 1KB-contiguous (8 CLs).
// ---------------------------------------------------------------------------
__global__ __launch_bounds__(256) void qkv_kernel(const float* __restrict__ X,
                                                  const u16* __restrict__ Wt,
                                                  const float* __restrict__ bias,
                                                  u16* __restrict__ Q,
                                                  u16* __restrict__ K,
                                                  u16* __restrict__ Vt){
  __shared__ __align__(16) u16 S[64*68];  // 8704 B staging
  int bid = blockIdx.x;
  int xcd = bid & 7;
  int idx = bid >> 3;                     // 0..191
  int mt  = 8*(idx & 15) + xcd;           // m-tile 0..127
  int nb  = idx >> 4;                     // 0..11
  int tid = threadIdx.x;
  int wave = tid >> 6, lane = tid & 63;
  int l16 = lane & 15, quad = lane >> 4;
  int m0 = mt * 64;
  int mw = m0 + wave * 16;
  int n0 = nb * 64;                       // 64 output cols (uniform q/k/v)
  const int three = n0 >> 8;              // 0=q 1=k 2=v (block-uniform)

  // ---- A-frags: x row (mw+l16), 8 chunks of 8 floats -> bf16 ----
  const float* xr = X + (mw + l16) * 256 + quad * 8;
  U8 af[8];
#pragma unroll
  for (int k = 0; k < 8; ++k){
    f32x4 lo = *(const f32x4*)(xr + k*32);
    f32x4 hi = *(const f32x4*)(xr + k*32 + 4);
    union { u32 w[4]; u16x8 u; } pk;
    pk.w[0] = pk2bf(lo[0], lo[1]);
    pk.w[1] = pk2bf(lo[2], lo[3]);
    pk.w[2] = pk2bf(hi[0], hi[1]);
    pk.w[3] = pk2bf(hi[2], hi[3]);
    af[k].u = pk.u;
  }

  // ---- MFMA over K=256 ----
  f32x4 acc[4] = {};
#pragma unroll
  for (int k = 0; k < 8; ++k)
#pragma unroll
    for (int s = 0; s < 4; ++s){
      U8 b; b.u = *(const u16x8*)(Wt + (n0 + s*16 + l16)*256 + k*32 + quad*8);
      acc[s] = mfma_bf16(af[k].b, b.b, acc[s]);
    }

  // ---- epilogue ----
  int b_ = m0 >> 11, nseq0 = m0 & 2047;   // block rows all in one batch
  if (three == 2){
    // V: stage [col][tok]
#pragma unroll
    for (int s = 0; s < 4; ++s){
      int cl = s*16 + l16;
      float bv = bias[n0 + cl];
      int tok = wave*16 + quad*4;
      U2 pk;
      pk.w[0] = pk2bf(acc[s][0] + bv, acc[s][1] + bv);
      pk.w[1] = pk2bf(acc[s][2] + bv, acc[s][3] + bv);
      *(uint64_t*)(&S[cl*68 + tok]) = pk.q;
    }
    __syncthreads();
#pragma unroll
    for (int i = 0; i < 16; ++i){
      int cl = wave*16 + i;
      int c = n0 + cl;
      int h = (c >> 5) & 7, d = c & 31;
      int bh = b_*8 + h;
      int kb = (nseq0 >> 5) + (lane >> 5);
      int kk = lane & 31;
      Vt[((bh*64 + kb)*32 + d)*32 + kk] = S[cl*68 + lane];
    }
  } else {
    // Q/K: stage token-major [tok][col]
    float scl = (three == 0) ? QSCALE_LOG2E : 1.0f;
#pragma unroll
    for (int s = 0; s < 4; ++s){
      int cl = s*16 + l16;
      float bv = bias[n0 + cl];
#pragma unroll
      for (int r = 0; r < 4; ++r)
        S[(wave*16 + quad*4 + r)*68 + cl] = f2bf((acc[s][r] + bv) * scl);
    }
    __syncthreads();
    u16* dst = (three == 0) ? Q : K;
#pragma unroll
    for (int j = 0; j < 2; ++j){
      int unit = tid + j*256;             // 512 units: tok x ph x chunk
      int tok = unit & 63;
      int rest = unit >> 6;               // 0..7
      int ph = rest >> 2, chunk = rest & 3;
      int h = ((n0 >> 5) + ph) & 7;
      int bh = b_*8 + h;
      u16x8 v = *(const u16x8*)(&S[tok*68 + ph*32 + chunk*8]);
      *(u16x8*)(&dst[(bh*N_SEQ + nseq0 + tok)*HDIM + chunk*8]) = v;
    }
  }
}

// ---------------------------------------------------------------------------
// Kernel 3: attention.  Block = 32 q-rows of one bh; 4 waves k-split (stride
// 4); 32 queries share each K/V fragment load (halves L1 transactions/work).
// V is tiled [kb][d][kk] -> vf loads 1KB contiguous (8 CLs).  P per wave per
// q-group in LDS; Obuf ALIASES the P region (safe: barrier-separated).
// Grid 2048 XCD-swizzled; p = exp2(S) (Q pre-scaled by log2e).
// ---------------------------------------------------------------------------
__global__ __launch_bounds__(256, 4) void attn_kernel(const u16* __restrict__ Q,
                                                      const u16* __restrict__ Kg,
                                                      const u16* __restrict__ Vt,
                                                      float* __restrict__ out){
  __shared__ __align__(16) u16 smem[4*2*16*72];   // 18432 B (P | Obuf alias)
  __shared__ float Lbuf[4][32];
  u16  (*Ps)[2][16][72] = (u16 (*)[2][16][72])smem;
  float (*Obuf)[32][36] = (float (*)[32][36])smem;

  int bid = blockIdx.x;
  int bh = (bid & 7)*4 + ((bid >> 3) & 3);
  int g  = bid >> 5;                      // 0..63: 32-row q-group
  int r0 = g * 32;
  int tid = threadIdx.x, wave = tid >> 6, lane = tid & 63;
  int l16 = lane & 15, quad = lane >> 4;

  const u16* Qb = Q  + bh * (N_SEQ*HDIM);
  const u16* Kb = Kg + bh * (N_SEQ*HDIM);
  const u16* Vb = Vt + bh * (64*32*32);   // tiled [kb][d][kk]

  const int  T       = (r0 < 1024) ? 16 : ((r0 + 31) >> 6) + 1;
  const bool hasMask = (r0 >= 1024);

  U8 qt[2];
  qt[0].u = *(const u16x8*)(Qb + (r0      + l16)*HDIM + quad*8);
  qt[1].u = *(const u16x8*)(Qb + (r0 + 16 + l16)*HDIM + quad*8);

  U8 onesu;
#pragma unroll
  for (int j = 0; j < 8; ++j) onesu.u[j] = 0x3F80;   // bf16 1.0
  bf16x8 ones = onesu.b;

  f32x4 O[2][2] = {};
  f32x4 L[2] = {};

  for (int t = wave; t < T; t += 4){
    int k0 = t * 64;

    // K fragments: 16 rows x 64B = 1KB contiguous each
    U8 kf[4];
#pragma unroll
    for (int s = 0; s < 4; ++s)
      kf[s].u = *(const u16x8*)(Kb + (k0 + s*16 + l16)*HDIM + quad*8);
    // V fragments: tiled layout, 1KB contiguous each
    U8 vf[2][2];
#pragma unroll
    for (int kc = 0; kc < 2; ++kc)
#pragma unroll
      for (int nd = 0; nd < 2; ++nd)
        vf[kc][nd].u = *(const u16x8*)(Vb + (size_t)(t*2 + kc)*1024 + (nd*16 + l16)*32 + quad*8);

    bool mask = hasMask && (t == T - 1);

    // ---- scores + exp for both query groups ----
#pragma unroll
    for (int qg = 0; qg < 2; ++qg){
      f32x4 ST[4];
#pragma unroll
      for (int s = 0; s < 4; ++s){
        f32x4 z = {};
        ST[s] = mfma_bf16(kf[s].b, qt[qg].b, z);
      }
      u16 (*P)[72] = Ps[wave][qg];
      if (mask){
        int iq = r0 + qg*16 + l16;
#pragma unroll
        for (int s = 0; s < 4; ++s){
          int jb = k0 + s*16 + quad*4;
          float p0 = (jb+0 > iq) ? 0.0f : EXP2(ST[s][0]);
          float p1 = (jb+1 > iq) ? 0.0f : EXP2(ST[s][1]);
          float p2 = (jb+2 > iq) ? 0.0f : EXP2(ST[s][2]);
          float p3 = (jb+3 > iq) ? 0.0f : EXP2(ST[s][3]);
          U2 pk; pk.w[0] = pk2bf(p0, p1); pk.w[1] = pk2bf(p2, p3);
          *(uint64_t*)(&P[l16][s*16 + quad*4]) = pk.q;
        }
      } else {
#pragma unroll
        for (int s = 0; s < 4; ++s){
          U2 pk;
          pk.w[0] = pk2bf(EXP2(ST[s][0]), EXP2(ST[s][1]));
          pk.w[1] = pk2bf(EXP2(ST[s][2]), EXP2(ST[s][3]));
          *(uint64_t*)(&P[l16][s*16 + quad*4]) = pk.q;
        }
      }
    }

    // ---- PV + denominator for both query groups ----
#pragma unroll
    for (int qg = 0; qg < 2; ++qg){
      u16 (*P)[72] = Ps[wave][qg];
#pragma unroll
      for (int kc = 0; kc < 2; ++kc){
        U8 pf; pf.u = *(const u16x8*)(&P[l16][kc*32 + quad*8]);
        O[qg][0] = mfma_bf16(pf.b, vf[kc][0].b, O[qg][0]);
        O[qg][1] = mfma_bf16(pf.b, vf[kc][1].b, O[qg][1]);
        L[qg]    = mfma_bf16(pf.b, ones, L[qg]);
      }
    }
  }

  __syncthreads();   // all PV done -> safe to alias P region as Obuf

#pragma unroll
  for (int qg = 0; qg < 2; ++qg)
#pragma unroll
    for (int r = 0; r < 4; ++r){
      int row = qg*16 + quad*4 + r;
      Obuf[wave][row][l16]      = O[qg][0][r];
      Obuf[wave][row][16 + l16] = O[qg][1][r];
    }
  if (l16 == 0){
#pragma unroll
    for (int qg = 0; qg < 2; ++qg)
#pragma unroll
      for (int r = 0; r < 4; ++r)
        Lbuf[wave][qg*16 + quad*4 + r] = L[qg][r];
  }
  __syncthreads();

  // combine 4 key-splits: 256 threads = 32 rows x 8 col-quads
  {
    int row = tid >> 3;               // 0..31
    int c4  = (tid & 7) * 4;          // 0..28
    f32x4 a = *(const f32x4*)(&Obuf[0][row][c4]);
    float Ls = Lbuf[0][row];
#pragma unroll
    for (int w = 1; w < 4; ++w){
      f32x4 b = *(const f32x4*)(&Obuf[w][row][c4]);
      a[0] += b[0]; a[1] += b[1]; a[2] += b[2]; a[3] += b[3];
      Ls += Lbuf[w][row];
    }
    float inv = 1.0f / Ls;
    a[0] *= inv; a[1] *= inv; a[2] *= inv; a[3] *= inv;
    int b_ = bh >> 3, h = bh & 7;
    *(f32x4*)(&out[(b_*N_SEQ + r0 + row)*256 + h*32 + c4]) = a;
  }
}

// ---------------------------------------------------------------------------
extern "C" void kernel_launch(void* const* d_in, const int* in_sizes, int n_in,
                              void* d_out, int out_size, void* d_ws, size_t ws_size,
                              hipStream_t stream) {
  const float* x    = (const float*)d_in[0];   // [4,2048,256] fp32
  const float* W    = (const float*)d_in[1];   // [256,768]    fp32
  const float* bias = (const float*)d_in[2];   // [768]        fp32
  float* out = (float*)d_out;                  // [4,2048,256] fp32

  char* ws = (char*)d_ws;
  u16* Wt    = (u16*)(ws);                     // 393,216 B
  u16* Kbuf  = (u16*)(ws + 393216);            // 4 MB
  u16* Vtbuf = (u16*)(ws + 393216 + 4194304);  // 4 MB (tiled [bh][kb][d][kk])
  u16* Qbuf  = (u16*)(ws + 393216 + 2*4194304);// 4 MB

  wt_kernel  <<<dim3(24, 8), 256, 0, stream>>>(W, Wt);
  qkv_kernel <<<dim3(1536),  256, 0, stream>>>(x, Wt, bias, Qbuf, Kbuf, Vtbuf);
  attn_kernel<<<dim3(2048),  256, 0, stream>>>(Qbuf, Kbuf, Vtbuf, out);
}

// Round 11
// 120.404 us; speedup vs baseline: 1.7009x; 1.0405x over previous
//
#include <hip/hip_runtime.h>
#include <cstdint>
#include <cstddef>

typedef unsigned short u16;
typedef unsigned int u32;
typedef __attribute__((ext_vector_type(8))) __bf16 bf16x8;
typedef __attribute__((ext_vector_type(8))) u16 u16x8;
typedef __attribute__((ext_vector_type(4))) float f32x4;

#define N_SEQ   2048
#define HDIM    32
// (hd^-0.5) * log2(e): Q pre-scaled so attn uses bare exp2
#define QSCALE_LOG2E 0.2550540261150831f

#if __has_builtin(__builtin_amdgcn_exp2f)
#define EXP2(x) __builtin_amdgcn_exp2f(x)
#else
#define EXP2(x) exp2f(x)
#endif

__device__ __forceinline__ u16 f2bf(float f){
  union { float f; u32 i; } v; v.f = f;
  return (u16)((v.i + 0x7FFFu + ((v.i >> 16) & 1u)) >> 16);
}
__device__ __forceinline__ u32 fbits(float f){
  union { float f; u32 i; } v; v.f = f; return v.i;
}
__device__ __forceinline__ u32 pk2bf(float a, float b){
  return ((fbits(a) + 0x8000u) >> 16) | ((fbits(b) + 0x8000u) & 0xFFFF0000u);
}
__device__ __forceinline__ f32x4 mfma_bf16(bf16x8 a, bf16x8 b, f32x4 c){
  return __builtin_amdgcn_mfma_f32_16x16x32_bf16(a, b, c, 0, 0, 0);
}
union U8 { u16x8 u; bf16x8 b; };
union U2 { u32 w[2]; uint64_t q; };

// ---------------------------------------------------------------------------
// Kernel 1: W [256][768] fp32 -> Wtp, PACKED fragment-linear bf16:
// Wtp[((c>>4)*8 + (k>>5))*512 + (c&15)*32 + ((k>>3)&3)*8 + (k&7)]
// so a qkv B-fragment load is 1KB contiguous (8 CLs, fully coalesced).
// ---------------------------------------------------------------------------
__global__ __launch_bounds__(256) void wt_kernel(const float* __restrict__ W,
                                                 u16* __restrict__ Wtp){
  int t  = threadIdx.x;
  int tx = t & 31, ty = t >> 5;
  int n0 = blockIdx.x * 32;
  int k0 = blockIdx.y * 32;
#pragma unroll
  for (int i = 0; i < 4; ++i){
    int k = k0 + ty + i*8;
    int c = n0 + tx;
    u16 v = f2bf(W[k*768 + c]);
    Wtp[((c>>4)*8 + (k>>5))*512 + (c&15)*32 + ((k>>3)&3)*8 + (k&7)] = v;
  }
}

// ---------------------------------------------------------------------------
// Kernel 2: QKV = x @ W + b.  1D grid 1536, XCD-swizzled.  x staged to LDS
// via fully-coalesced f32x4 (was a 16-CL/inst register gather); B-frags read
// contiguous from packed Wtp.  Epilogue LDS-staged coalesced stores;
// V tiled Vt[bh][kb][d32][kk32].
// ---------------------------------------------------------------------------
__global__ __launch_bounds__(256) void qkv_kernel(const float* __restrict__ X,
                                                  const u16* __restrict__ Wtp,
                                                  const float* __restrict__ bias,
                                                  u16* __restrict__ Q,
                                                  u16* __restrict__ K,
                                                  u16* __restrict__ Vt){
  __shared__ __align__(16) u16 SM[64*264];  // 33.8 KB: x-stage, then epilogue
  int bid = blockIdx.x;
  int xcd = bid & 7;
  int idx = bid >> 3;                     // 0..191
  int mt  = 8*(idx & 15) + xcd;           // m-tile 0..127
  int nb  = idx >> 4;                     // 0..11
  int tid = threadIdx.x;
  int wave = tid >> 6, lane = tid & 63;
  int l16 = lane & 15, quad = lane >> 4;
  int m0 = mt * 64;
  int n0 = nb * 64;                       // 64 output cols (uniform q/k/v)
  const int three = n0 >> 8;              // 0=q 1=k 2=v (block-uniform)

  // ---- stage x tile [64][256] fp32 -> bf16 LDS, coalesced ----
  const float* Xblk = X + m0 * 256;
#pragma unroll
  for (int i = 0; i < 16; ++i){
    int e = i*1024 + tid*4;               // 4KB contiguous per i
    f32x4 v = *(const f32x4*)(Xblk + e);
    int row = e >> 8, col = e & 255;
    U2 pk; pk.w[0] = pk2bf(v[0], v[1]); pk.w[1] = pk2bf(v[2], v[3]);
    *(uint64_t*)(&SM[row*264 + col]) = pk.q;
  }
  __syncthreads();

  // ---- A-frags from LDS (row stride 528B = 33*16B, conflict-benign) ----
  int mrow = wave*16 + l16;
  U8 af[8];
#pragma unroll
  for (int k = 0; k < 8; ++k)
    af[k].u = *(const u16x8*)(&SM[mrow*264 + k*32 + quad*8]);
  __syncthreads();                        // SM reused by epilogue below

  // ---- MFMA over K=256; B-frags 1KB contiguous from packed Wtp ----
  f32x4 acc[4] = {};
#pragma unroll
  for (int k = 0; k < 8; ++k)
#pragma unroll
    for (int s = 0; s < 4; ++s){
      U8 b;
      b.u = *(const u16x8*)(Wtp + (((n0>>4) + s)*8 + k)*512 + l16*32 + quad*8);
      acc[s] = mfma_bf16(af[k].b, b.b, acc[s]);
    }

  // ---- epilogue ----
  int b_ = m0 >> 11, nseq0 = m0 & 2047;
  if (three == 2){
    // V: stage [col][tok]
#pragma unroll
    for (int s = 0; s < 4; ++s){
      int cl = s*16 + l16;
      float bv = bias[n0 + cl];
      int tok = wave*16 + quad*4;
      U2 pk;
      pk.w[0] = pk2bf(acc[s][0] + bv, acc[s][1] + bv);
      pk.w[1] = pk2bf(acc[s][2] + bv, acc[s][3] + bv);
      *(uint64_t*)(&SM[cl*68 + tok]) = pk.q;
    }
    __syncthreads();
#pragma unroll
    for (int i = 0; i < 16; ++i){
      int cl = wave*16 + i;
      int c = n0 + cl;
      int h = (c >> 5) & 7, d = c & 31;
      int bh = b_*8 + h;
      int kb = (nseq0 >> 5) + (lane >> 5);
      int kk = lane & 31;
      Vt[((bh*64 + kb)*32 + d)*32 + kk] = SM[cl*68 + lane];
    }
  } else {
    // Q/K: stage token-major [tok][col]
    float scl = (three == 0) ? QSCALE_LOG2E : 1.0f;
#pragma unroll
    for (int s = 0; s < 4; ++s){
      int cl = s*16 + l16;
      float bv = bias[n0 + cl];
#pragma unroll
      for (int r = 0; r < 4; ++r)
        SM[(wave*16 + quad*4 + r)*68 + cl] = f2bf((acc[s][r] + bv) * scl);
    }
    __syncthreads();
    u16* dst = (three == 0) ? Q : K;
#pragma unroll
    for (int j = 0; j < 2; ++j){
      int unit = tid + j*256;             // 512 units: tok x ph x chunk
      int tok = unit & 63;
      int rest = unit >> 6;               // 0..7
      int ph = rest >> 2, chunk = rest & 3;
      int h = ((n0 >> 5) + ph) & 7;
      int bh = b_*8 + h;
      u16x8 v = *(const u16x8*)(&SM[tok*68 + ph*32 + chunk*8]);
      *(u16x8*)(&dst[(bh*N_SEQ + nseq0 + tok)*HDIM + chunk*8]) = v;
    }
  }
}

// ---------------------------------------------------------------------------
// Kernel 3: attention.  Block = 64 q-rows of one bh (4 qg of 16), 4 waves
// k-split (stride 4).  K frags held in regs across both qg-pairs: per tile
// 4 K-loads + 8 V-loads serve 64 queries (R10: 16 loads per 64q).  Grid 1024
// XCD-swizzled -> ALL blocks co-resident (4/CU).  P double-buffer per wave
// (2 sub-slots, reused across pairs -- same-wave lgkm ordering).  Obuf
// aliases P region; epilogue in 2 passes of 32 rows.
// ---------------------------------------------------------------------------
__global__ __launch_bounds__(256, 4) void attn_kernel(const u16* __restrict__ Q,
                                                      const u16* __restrict__ Kg,
                                                      const u16* __restrict__ Vt,
                                                      float* __restrict__ out){
  __shared__ __align__(16) u16 smem[4*2*16*72];   // 18432 B (P | Obuf alias)
  __shared__ float Lbuf[4][32];
  u16  (*Ps)[2][16][72] = (u16 (*)[2][16][72])smem;
  float (*Obuf)[32][36] = (float (*)[32][36])smem;

  int bid = blockIdx.x;
  int bh = (bid & 7)*4 + ((bid >> 3) & 3);
  int g  = bid >> 5;                      // 0..31: 64-row q-group
  int r0 = g * 64;
  int tid = threadIdx.x, wave = tid >> 6, lane = tid & 63;
  int l16 = lane & 15, quad = lane >> 4;

  const u16* Qb = Q  + bh * (N_SEQ*HDIM);
  const u16* Kb = Kg + bh * (N_SEQ*HDIM);
  const u16* Vb = Vt + bh * (64*32*32);   // tiled [kb][d][kk]

  const int  T       = (r0 < 1024) ? 16 : (g + 1);
  const bool hasMask = (r0 >= 1024);

  U8 qt[4];
#pragma unroll
  for (int qg = 0; qg < 4; ++qg)
    qt[qg].u = *(const u16x8*)(Qb + (r0 + qg*16 + l16)*HDIM + quad*8);

  U8 onesu;
#pragma unroll
  for (int j = 0; j < 8; ++j) onesu.u[j] = 0x3F80;   // bf16 1.0
  bf16x8 ones = onesu.b;

  f32x4 O[4][2] = {};
  f32x4 L[4] = {};

  for (int t = wave; t < T; t += 4){
    int k0 = t * 64;
    // K fragments: 1KB contiguous each; held across both qg-pairs
    U8 kf[4];
#pragma unroll
    for (int s = 0; s < 4; ++s)
      kf[s].u = *(const u16x8*)(Kb + (k0 + s*16 + l16)*HDIM + quad*8);

    bool mask = hasMask && (t == T - 1);

#pragma unroll
    for (int pr = 0; pr < 2; ++pr){
      // ---- QK + exp for qg = 2pr, 2pr+1 ----
#pragma unroll
      for (int sub = 0; sub < 2; ++sub){
        int qg = pr*2 + sub;
        f32x4 ST[4];
#pragma unroll
        for (int s = 0; s < 4; ++s){
          f32x4 z = {};
          ST[s] = mfma_bf16(kf[s].b, qt[qg].b, z);
        }
        u16 (*P)[72] = Ps[wave][sub];
        if (mask){
          int iq = r0 + qg*16 + l16;
#pragma unroll
          for (int s = 0; s < 4; ++s){
            int jb = k0 + s*16 + quad*4;
            float p0 = (jb+0 > iq) ? 0.0f : EXP2(ST[s][0]);
            float p1 = (jb+1 > iq) ? 0.0f : EXP2(ST[s][1]);
            float p2 = (jb+2 > iq) ? 0.0f : EXP2(ST[s][2]);
            float p3 = (jb+3 > iq) ? 0.0f : EXP2(ST[s][3]);
            U2 pk; pk.w[0] = pk2bf(p0, p1); pk.w[1] = pk2bf(p2, p3);
            *(uint64_t*)(&P[l16][s*16 + quad*4]) = pk.q;
          }
        } else {
#pragma unroll
          for (int s = 0; s < 4; ++s){
            U2 pk;
            pk.w[0] = pk2bf(EXP2(ST[s][0]), EXP2(ST[s][1]));
            pk.w[1] = pk2bf(EXP2(ST[s][2]), EXP2(ST[s][3]));
            *(uint64_t*)(&P[l16][s*16 + quad*4]) = pk.q;
          }
        }
      }

      // ---- V fragments (1KB contiguous), then PV for both qg of pair ----
      U8 vf[2][2];
#pragma unroll
      for (int kc = 0; kc < 2; ++kc)
#pragma unroll
        for (int nd = 0; nd < 2; ++nd)
          vf[kc][nd].u = *(const u16x8*)(Vb + (size_t)(t*2 + kc)*1024 + (nd*16 + l16)*32 + quad*8);

#pragma unroll
      for (int sub = 0; sub < 2; ++sub){
        int qg = pr*2 + sub;
        u16 (*P)[72] = Ps[wave][sub];
#pragma unroll
        for (int kc = 0; kc < 2; ++kc){
          U8 pf; pf.u = *(const u16x8*)(&P[l16][kc*32 + quad*8]);
          O[qg][0] = mfma_bf16(pf.b, vf[kc][0].b, O[qg][0]);
          O[qg][1] = mfma_bf16(pf.b, vf[kc][1].b, O[qg][1]);
          L[qg]    = mfma_bf16(pf.b, ones, L[qg]);
        }
      }
    }
  }

  __syncthreads();   // all PV done -> safe to alias P region as Obuf

  int b_ = bh >> 3, h = bh & 7;
#pragma unroll
  for (int pass = 0; pass < 2; ++pass){
    if (pass) __syncthreads();
#pragma unroll
    for (int sub = 0; sub < 2; ++sub){
      int qg = pass*2 + sub;
#pragma unroll
      for (int r = 0; r < 4; ++r){
        int row = sub*16 + quad*4 + r;
        Obuf[wave][row][l16]      = O[qg][0][r];
        Obuf[wave][row][16 + l16] = O[qg][1][r];
      }
      if (l16 == 0){
#pragma unroll
        for (int r = 0; r < 4; ++r)
          Lbuf[wave][sub*16 + quad*4 + r] = L[qg][r];
      }
    }
    __syncthreads();
    {
      int row = tid >> 3;               // 0..31
      int c4  = (tid & 7) * 4;          // 0..28
      f32x4 a = *(const f32x4*)(&Obuf[0][row][c4]);
      float Ls = Lbuf[0][row];
#pragma unroll
      for (int w = 1; w < 4; ++w){
        f32x4 b = *(const f32x4*)(&Obuf[w][row][c4]);
        a[0] += b[0]; a[1] += b[1]; a[2] += b[2]; a[3] += b[3];
        Ls += Lbuf[w][row];
      }
      float inv = 1.0f / Ls;
      a[0] *= inv; a[1] *= inv; a[2] *= inv; a[3] *= inv;
      *(f32x4*)(&out[(b_*N_SEQ + r0 + pass*32 + row)*256 + h*32 + c4]) = a;
    }
  }
}

// ---------------------------------------------------------------------------
extern "C" void kernel_launch(void* const* d_in, const int* in_sizes, int n_in,
                              void* d_out, int out_size, void* d_ws, size_t ws_size,
                              hipStream_t stream) {
  const float* x    = (const float*)d_in[0];   // [4,2048,256] fp32
  const float* W    = (const float*)d_in[1];   // [256,768]    fp32
  const float* bias = (const float*)d_in[2];   // [768]        fp32
  float* out = (float*)d_out;                  // [4,2048,256] fp32

  char* ws = (char*)d_ws;
  u16* Wtp   = (u16*)(ws);                     // 393,216 B packed
  u16* Kbuf  = (u16*)(ws + 393216);            // 4 MB
  u16* Vtbuf = (u16*)(ws + 393216 + 4194304);  // 4 MB (tiled [bh][kb][d][kk])
  u16* Qbuf  = (u16*)(ws + 393216 + 2*4194304);// 4 MB

  wt_kernel  <<<dim3(24, 8), 256, 0, stream>>>(W, Wtp);
  qkv_kernel <<<dim3(1536),  256, 0, stream>>>(x, Wtp, bias, Qbuf, Kbuf, Vtbuf);
  attn_kernel<<<dim3(1024),  256, 0, stream>>>(Qbuf, Kbuf, Vtbuf, out);
}